// Round 11
// baseline (285.228 us; speedup 1.0000x reference)
//
#include <hip/hip_runtime.h>
#include <hip/hip_cooperative_groups.h>

namespace cg = cooperative_groups;

typedef float  f32x4   __attribute__((ext_vector_type(4)));
typedef float  f32x16  __attribute__((ext_vector_type(16)));
typedef short  bf16x8  __attribute__((ext_vector_type(8)));
typedef unsigned short u16;

constexpr int B_ = 4;
constexpr int C_ = 128;
constexpr int N_ = 4096;
constexpr int G_ = 8;
constexpr int CperG = 16;
constexpr float EPS_ = 1e-5f;
constexpr float SCALE_ = 0.08838834764831845f;  // 1/sqrt(C)
constexpr int HS = 136;   // padded row stride (u16)

__device__ inline u16 f2bf(float f) {
    union { float f; unsigned u; } v; v.f = f;
    unsigned r = v.u + 0x7fffu + ((v.u >> 16) & 1u);  // RNE
    return (u16)(r >> 16);
}
__device__ inline unsigned pk2(float a, float b) {
    return (unsigned)f2bf(a) | ((unsigned)f2bf(b) << 16);
}

// ---------------- fused cooperative kernel: prep | qkv | attn ----------------
// 256 blocks x 512 threads, 1 block/CU (LDS ~88 KB). grid.sync() between phases.
__global__ __launch_bounds__(512, 2) void fused_kernel(const float* __restrict__ x,
                                                       const float* __restrict__ nw,
                                                       const float* __restrict__ nb,
                                                       const float* __restrict__ qw,
                                                       const float* __restrict__ qb,
                                                       const float* __restrict__ pw,
                                                       const float* __restrict__ pb,
                                                       float* __restrict__ stats2,
                                                       float* __restrict__ qn2,
                                                       int* __restrict__ kmaxI,
                                                       u16* __restrict__ qwbf,
                                                       u16* __restrict__ pwbf,
                                                       u16* __restrict__ Qt,
                                                       u16* __restrict__ Ksw,
                                                       u16* __restrict__ Vsw,
                                                       float* __restrict__ out) {
    cg::grid_group grid = cg::this_grid();

    __shared__ u16 hs[64 * HS];        // 17.4 KB  (phase B)
    __shared__ u16 Wl[128 * HS];       // 34.8 KB  (phase B: two 64-row chunks)
    __shared__ float Ob[64 * 132];     // 33.8 KB  (phase C)
    __shared__ float lW[8][32];
    __shared__ float rs[8], rss[8];
    __shared__ float gmean[8], grstd[8];
    __shared__ float nqS[2][64], nkS[2][64];

    int blk = blockIdx.x;
    int t = threadIdx.x;
    int w = t >> 6, lane = t & 63, lo = lane & 15, hi = lane >> 4;

    // ================= Phase A: GN partials + weight bf16 conversion =================
    {
        int bg = blk >> 3, chunk = blk & 7;
        const float4* xp = (const float4*)(x + (size_t)bg * (CperG * N_)) + chunk * 2048;
        float s = 0.f, ss = 0.f;
        #pragma unroll
        for (int r = 0; r < 4; ++r) {
            float4 v = xp[t + (r << 9)];
            s  += v.x + v.y + v.z + v.w;
            ss += v.x*v.x + v.y*v.y + v.z*v.z + v.w*v.w;
        }
        #pragma unroll
        for (int off = 32; off > 0; off >>= 1) {
            s  += __shfl_down(s, off);
            ss += __shfl_down(ss, off);
        }
        if (lane == 0) { rs[w] = s; rss[w] = ss; }
        // weight conversion: 16384 float4 total / 256 blocks = 64 per block
        if (t < 64) {
            int fidx = (blk*64 + t) * 4;
            float4 v;
            u16* dst;
            if (fidx < 3*C_*C_) { v = *(const float4*)(qw + fidx); dst = qwbf + fidx; }
            else { int j = fidx - 3*C_*C_; v = *(const float4*)(pw + j); dst = pwbf + j; }
            ushort4 o;
            o.x = f2bf(v.x); o.y = f2bf(v.y); o.z = f2bf(v.z); o.w = f2bf(v.w);
            *(ushort4*)dst = o;
        }
        __syncthreads();
        if (t == 0) {
            float S = 0.f, SS = 0.f;
            #pragma unroll
            for (int i = 0; i < 8; ++i) { S += rs[i]; SS += rss[i]; }
            stats2[blk*2]     = S;
            stats2[blk*2 + 1] = SS;
        }
    }
    __threadfence();
    grid.sync();

    // ================= Phase B: QKV via MFMA -> Qt + fragment-order Ksw/Vsw ==========
    {
        int n0 = (blk & 63) * 64;
        int b  = blk >> 6;
        const float invM = 1.f / (float)(CperG * N_);
        if (t < 8) {
            const float* sp = stats2 + (size_t)(b*G_ + t)*16;
            float S = 0.f, SS = 0.f;
            #pragma unroll
            for (int k2 = 0; k2 < 8; ++k2) { S += sp[k2*2]; SS += sp[k2*2 + 1]; }
            float mean = S * invM;
            gmean[t] = mean;
            grstd[t] = rsqrtf(SS * invM - mean*mean + EPS_);
        }
        __syncthreads();
        // stage h: 64 px x 128 c, [px][c] padded (512 threads, 4 rounds)
        #pragma unroll
        for (int r = 0; r < 4; ++r) {
            int idx = t + (r << 9);
            int c = idx >> 4, n4 = idx & 15;
            int g = c >> 4;
            float wgt = nw[c] * grstd[g];
            float bia = nb[c] - gmean[g] * wgt;
            float4 xv = *(const float4*)(x + ((size_t)(b*C_ + c))*N_ + n0 + n4*4);
            int base = (n4*4) * HS + c;
            hs[base         ] = f2bf(xv.x*wgt + bia);
            hs[base +     HS] = f2bf(xv.y*wgt + bia);
            hs[base + 2 * HS] = f2bf(xv.z*wgt + bia);
            hs[base + 3 * HS] = f2bf(xv.w*wgt + bia);
        }
        __syncthreads();
        int g2 = w >> 2;       // wave group: which chunk of the pair
        int wl = w & 3;        // pixel group within block
        bf16x8 hf[4];
        #pragma unroll
        for (int ch = 0; ch < 4; ++ch)
            hf[ch] = *(const bf16x8*)(hs + (16*wl + lo)*HS + 32*ch + 8*hi);

        int Tb = (n0 >> 5) + (wl >> 1);
        float nq = 0.f, nk = 0.f;
        for (int ck2 = 0; ck2 < 3; ++ck2) {
            // stage TWO 64-row W chunks (128 rows) with 512 threads
            {
                int r = t >> 2, p = t & 3;
                const u16* src = qwbf + (size_t)(ck2*128 + r)*C_ + p*32;
                u16* dst = Wl + r*HS + p*32;
                #pragma unroll
                for (int k2 = 0; k2 < 4; ++k2)
                    *(uint4*)(dst + 8*k2) = *(const uint4*)(src + 8*k2);
            }
            __syncthreads();
            int chunk = ck2*2 + g2;
            #pragma unroll
            for (int ot = 0; ot < 4; ++ot) {
                int o16 = chunk*64 + ot*16;
                bf16x8 wf[4];
                #pragma unroll
                for (int ch = 0; ch < 4; ++ch)
                    wf[ch] = *(const bf16x8*)(Wl + (64*g2 + ot*16 + lo)*HS + 32*ch + 8*hi);
                if (o16 < 2*C_) {
                    // Q/K: A=W (m=o), B=h (n=px) -> lane: D[o16+4hi+r][n0+16wl+lo]
                    f32x4 acc = (f32x4){0.f, 0.f, 0.f, 0.f};
                    #pragma unroll
                    for (int ch = 0; ch < 4; ++ch)
                        acc = __builtin_amdgcn_mfma_f32_16x16x32_bf16(wf[ch], hf[ch], acc, 0, 0, 0);
                    float4 bv = *(const float4*)(qb + o16 + 4*hi);
                    int n = n0 + 16*wl + lo;
                    ushort4 o4;
                    if (o16 < C_) {
                        float q0 = (acc[0] + bv.x) * SCALE_;
                        float q1 = (acc[1] + bv.y) * SCALE_;
                        float q2 = (acc[2] + bv.z) * SCALE_;
                        float q3 = (acc[3] + bv.w) * SCALE_;
                        nq += (q0*q0 + q1*q1) + (q2*q2 + q3*q3);
                        o4.x = f2bf(q0); o4.y = f2bf(q1); o4.z = f2bf(q2); o4.w = f2bf(q3);
                        *(ushort4*)(Qt + ((size_t)b*N_ + n)*C_ + o16 + 4*hi) = o4;
                    } else {
                        float k0 = acc[0] + bv.x, k1 = acc[1] + bv.y;
                        float k2 = acc[2] + bv.z, k3 = acc[3] + bv.w;
                        nk += (k0*k0 + k1*k1) + (k2*k2 + k3*k3);
                        o4.x = f2bf(k0); o4.y = f2bf(k1); o4.z = f2bf(k2); o4.w = f2bf(k3);
                        int cc = (o16 - C_) >> 4;
                        int lp = (16*(wl & 1) + lo) + 32*(hi >> 1);
                        size_t fb = ((size_t)(b*128 + Tb)*8 + cc)*512;
                        *(ushort4*)(Ksw + fb + lp*8 + 4*(hi & 1)) = o4;
                    }
                } else {
                    // V: A=h (m=px), B=W (n=o) -> lane: D[n0+16wl+4hi+r][o16-256+lo]
                    f32x4 acc = (f32x4){0.f, 0.f, 0.f, 0.f};
                    #pragma unroll
                    for (int ch = 0; ch < 4; ++ch)
                        acc = __builtin_amdgcn_mfma_f32_16x16x32_bf16(hf[ch], wf[ch], acc, 0, 0, 0);
                    float bia = qb[o16 + lo];
                    ushort4 o4;
                    o4.x = f2bf(acc[0] + bia);
                    o4.y = f2bf(acc[1] + bia);
                    o4.z = f2bf(acc[2] + bia);
                    o4.w = f2bf(acc[3] + bia);
                    int m  = (o16 - 2*C_) >> 4;
                    int ct = m >> 1;
                    int lp = (16*(m & 1) + lo) + 32*(hi & 1);
                    size_t fb = (((size_t)(b*4 + ct)*128 + Tb)*2 + (wl & 1))*512;
                    *(ushort4*)(Vsw + fb + lp*8 + 4*(hi >> 1)) = o4;
                }
            }
            __syncthreads();
        }
        // combine the two wave-groups' norm partials
        nq += __shfl_xor(nq, 16); nq += __shfl_xor(nq, 32);
        nk += __shfl_xor(nk, 16); nk += __shfl_xor(nk, 32);
        if (lane < 16) { nqS[g2][16*wl + lo] = nq; nkS[g2][16*wl + lo] = nk; }
        __syncthreads();
        if (w < 4) {
            float nqt = nqS[0][16*w + lo] + nqS[1][16*w + lo];
            float nkt = nkS[0][16*w + lo] + nkS[1][16*w + lo];
            if (lane < 16) qn2[(size_t)b*N_ + n0 + 16*w + lo] = nqt;
            #pragma unroll
            for (int off = 1; off < 16; off <<= 1)
                nkt = fmaxf(nkt, __shfl_xor(nkt, off));
            if (lane == 0) atomicMax(&kmaxI[b], __float_as_int(nkt));  // poison<0: safe
        }
    }
    __threadfence();
    grid.sync();

    // ================= Phase C: streaming MFMA attention (r10-identical) =============
    {
        int b  = blk & 3;                  // XCD-swizzle
        int i0 = 64 * (blk >> 2);
        int l31 = lane & 31, h = lane >> 5;
        int qt = w >> 2, ks = w & 3;

        float kmax = sqrtf(__int_as_float(kmaxI[b]));
        float mq = sqrtf(qn2[(size_t)b*N_ + i0 + 32*qt + l31]) * kmax * 1.02f + 1e-6f;

        const u16* Qb = Qt + (size_t)b*N_*C_;
        bf16x8 qf[8];
        #pragma unroll
        for (int cc = 0; cc < 8; ++cc)
            qf[cc] = *(const bf16x8*)(Qb + (size_t)(i0 + 32*qt + l31)*C_ + 16*cc + 8*h);

        f32x16 acc[4];
        #pragma unroll
        for (int ct = 0; ct < 4; ++ct)
            #pragma unroll
            for (int r = 0; r < 16; ++r) acc[ct][r] = 0.f;
        float psum = 0.f;

        const u16* Kbase = Ksw + ((size_t)(b*128 + ks*32)*8)*512;
        bf16x8 kf[8], kn[8];
        #pragma unroll
        for (int cc = 0; cc < 8; ++cc)
            kf[cc] = *(const bf16x8*)(Kbase + cc*512 + lane*8);

        for (int it = 0; it < 32; ++it) {
            f32x16 s;
            #pragma unroll
            for (int r = 0; r < 16; ++r) s[r] = 0.f;
            #pragma unroll
            for (int cc = 0; cc < 8; ++cc)
                s = __builtin_amdgcn_mfma_f32_32x32x16_bf16(kf[cc], qf[cc], s, 0, 0, 0);
            {
                const u16* Kn = Kbase + ((size_t)(((it + 1) & 31))*8)*512;
                #pragma unroll
                for (int cc = 0; cc < 8; ++cc)
                    kn[cc] = *(const bf16x8*)(Kn + cc*512 + lane*8);
            }
            int T = ks*32 + it;
            bf16x8 v1[4], v2[4];
            #pragma unroll
            for (int ct = 0; ct < 4; ++ct) {
                const u16* vb = Vsw + (((size_t)(b*4 + ct)*128 + T)*2)*512;
                v1[ct] = *(const bf16x8*)(vb + lane*8);
                v2[ct] = *(const bf16x8*)(vb + 512 + lane*8);
            }
            float p[16];
            #pragma unroll
            for (int r = 0; r < 16; ++r) {
                p[r] = __expf(s[r] - mq);
                psum += p[r];
            }
            union { bf16x8 v; unsigned u[4]; } pf1, pf2;
            pf1.u[0] = pk2(p[0],  p[1]);  pf1.u[1] = pk2(p[2],  p[3]);
            pf1.u[2] = pk2(p[4],  p[5]);  pf1.u[3] = pk2(p[6],  p[7]);
            pf2.u[0] = pk2(p[8],  p[9]);  pf2.u[1] = pk2(p[10], p[11]);
            pf2.u[2] = pk2(p[12], p[13]); pf2.u[3] = pk2(p[14], p[15]);
            #pragma unroll
            for (int ct = 0; ct < 4; ++ct) {
                acc[ct] = __builtin_amdgcn_mfma_f32_32x32x16_bf16(v1[ct], pf1.v, acc[ct], 0, 0, 0);
                acc[ct] = __builtin_amdgcn_mfma_f32_32x32x16_bf16(v2[ct], pf2.v, acc[ct], 0, 0, 0);
            }
            #pragma unroll
            for (int cc = 0; cc < 8; ++cc) kf[cc] = kn[cc];
        }

        // combine ks stripes (plain adds: shared m_q)
        psum += __shfl_xor(psum, 32);
        if (lane < 32) lW[w][l31] = psum;
        __syncthreads();
        for (int i = 0; i < 4; ++i) {
            if (ks == i) {
                int q = 32*qt + l31;
                #pragma unroll
                for (int ct = 0; ct < 4; ++ct)
                    #pragma unroll
                    for (int qd = 0; qd < 4; ++qd) {
                        int c = 32*ct + 8*qd + 4*h;
                        float4 vv;
                        vv.x = acc[ct][4*qd + 0];
                        vv.y = acc[ct][4*qd + 1];
                        vv.z = acc[ct][4*qd + 2];
                        vv.w = acc[ct][4*qd + 3];
                        if (i == 0) {
                            *(float4*)(Ob + q*132 + c) = vv;
                        } else {
                            float4 o = *(const float4*)(Ob + q*132 + c);
                            o.x += vv.x; o.y += vv.y; o.z += vv.z; o.w += vv.w;
                            *(float4*)(Ob + q*132 + c) = o;
                        }
                    }
            }
            __syncthreads();
        }
        // proj + bias + residual
        int qtile = w >> 1, os = w & 1;
        int q = 16*qtile + lo;
        int qg = 4*(q >> 5), qc = q & 31;
        float linv = 1.f / (lW[qg][qc] + lW[qg+1][qc] + lW[qg+2][qc] + lW[qg+3][qc]);
        bf16x8 aa[4];
        #pragma unroll
        for (int ch = 0; ch < 4; ++ch) {
            float4 ua = *(const float4*)(Ob + q*132 + 32*ch + 8*hi);
            float4 ub = *(const float4*)(Ob + q*132 + 32*ch + 8*hi + 4);
            union { bf16x8 hh; unsigned u[4]; } pkd;
            pkd.u[0] = pk2(ua.x*linv, ua.y*linv);
            pkd.u[1] = pk2(ua.z*linv, ua.w*linv);
            pkd.u[2] = pk2(ub.x*linv, ub.y*linv);
            pkd.u[3] = pk2(ub.z*linv, ub.w*linv);
            aa[ch] = pkd.hh;
        }
        #pragma unroll
        for (int ot = 0; ot < 4; ++ot) {
            int ob = 64*os + 16*ot;
            f32x4 pr = (f32x4){0.f, 0.f, 0.f, 0.f};
            #pragma unroll
            for (int ch = 0; ch < 4; ++ch) {
                bf16x8 bw = *(const bf16x8*)(pwbf + (size_t)(ob + lo)*C_ + 32*ch + 8*hi);
                pr = __builtin_amdgcn_mfma_f32_16x16x32_bf16(aa[ch], bw, pr, 0, 0, 0);
            }
            int o = ob + lo;
            float pbv = pb[o];
            size_t base = ((size_t)(b*C_ + o))*N_ + i0 + 16*qtile + 4*hi;
            float4 xr = *(const float4*)(x + base);
            float4 res;
            res.x = xr.x + pr[0] + pbv;
            res.y = xr.y + pr[1] + pbv;
            res.z = xr.z + pr[2] + pbv;
            res.w = xr.w + pr[3] + pbv;
            *(float4*)(out + base) = res;
        }
    }
}

extern "C" void kernel_launch(void* const* d_in, const int* in_sizes, int n_in,
                              void* d_out, int out_size, void* d_ws, size_t ws_size,
                              hipStream_t stream) {
    const float* x  = (const float*)d_in[0];
    const float* nw = (const float*)d_in[1];
    const float* nb = (const float*)d_in[2];
    const float* qw = (const float*)d_in[3];
    const float* qb = (const float*)d_in[4];
    const float* pw = (const float*)d_in[5];
    const float* pb = (const float*)d_in[6];
    float* out = (float*)d_out;

    // ws: [stats2 2KB][qn2 64KB][kmaxI 256B][qwbf 96KB][pwbf 32KB][Qt 4MB][Ksw 4MB][Vsw 4MB]
    char* p = (char*)d_ws;
    float* stats2 = (float*)p;                 p += 2048;
    float* qn2    = (float*)p;                 p += (size_t)B_*N_*4;
    int*   kmaxI  = (int*)p;                   p += 256;
    u16*   qwbf   = (u16*)p;                   p += (size_t)3*C_*C_*2;
    u16*   pwbf   = (u16*)p;                   p += (size_t)C_*C_*2;
    u16*   Qt     = (u16*)p;                   p += (size_t)B_*N_*C_*2;
    u16*   Ksw    = (u16*)p;                   p += (size_t)B_*N_*C_*2;
    u16*   Vsw    = (u16*)p;

    void* args[] = {
        (void*)&x, (void*)&nw, (void*)&nb, (void*)&qw, (void*)&qb,
        (void*)&pw, (void*)&pb,
        (void*)&stats2, (void*)&qn2, (void*)&kmaxI,
        (void*)&qwbf, (void*)&pwbf, (void*)&Qt, (void*)&Ksw, (void*)&Vsw,
        (void*)&out
    };
    hipLaunchCooperativeKernel((void*)fused_kernel, dim3(256), dim3(512),
                               args, 0, stream);
}